// Round 3
// baseline (338.280 us; speedup 1.0000x reference)
//
#include <hip/hip_runtime.h>
#include <stdint.h>

typedef unsigned short u16;
typedef __attribute__((ext_vector_type(8))) short short8;
typedef __attribute__((ext_vector_type(4))) float f32x4;

#define B_      16
#define L_      1024
#define H_      1024
#define G_      128
#define M_TOT   16368            // B*(L-1)
#define K_TOT   3072
#define OUT_SEG 2095104          // M_TOT*G_
#define KL_IDX  (4*OUT_SEG)
#define KL_BLOCKS 4092           // M_TOT / 4 exactly
#define NKT     48               // K_TOT / 64

// ws layout
#define WS_WT_OFF    0           // bf16 W'T [512][3072] = 3,145,728 B
#define WS_BIAS_OFF  3145728     // float[512]
#define WS_PART_OFF  3147776     // float[4092] block partials

__device__ inline u16 f2bf(float f) {
    union { float f; uint32_t u; } x; x.f = f;
    uint32_t u = x.u;
    return (u16)((u + 0x7fffu + ((u >> 16) & 1u)) >> 16);
}

__device__ inline void gload16(const void* g, void* l) {
    __builtin_amdgcn_global_load_lds(
        (const __attribute__((address_space(1))) void*)g,
        (__attribute__((address_space(3))) void*)l, 16, 0, 0);
}

// ---------------- prep: build W'T (bf16, [512][3072]) + bias[512] ------------
__global__ __launch_bounds__(256) void prep_kernel(
    const float* __restrict__ Wzm, const float* __restrict__ bzm,
    const float* __restrict__ Wzv, const float* __restrict__ bzv,
    const float* __restrict__ Wqm, const float* __restrict__ bqm,
    const float* __restrict__ Wqv, const float* __restrict__ bqv,
    u16* __restrict__ wt, float* __restrict__ bias)
{
    int n = blockIdx.x;                 // 0..511 (output column)
    int tid = threadIdx.x;
    const float* W; const float* bsrc; int g; int kmax;
    if (n < 128)      { W = Wzm; bsrc = bzm; g = n;       kmax = 2048; }
    else if (n < 256) { W = Wzv; bsrc = bzv; g = n - 128; kmax = 2048; }
    else if (n < 384) { W = Wqm; bsrc = bqm; g = n - 256; kmax = 3072; }
    else              { W = Wqv; bsrc = bqv; g = n - 384; kmax = 3072; }
    if (tid == 0) bias[n] = bsrc[g];
    #pragma unroll
    for (int i = 0; i < 12; ++i) {
        int k = i * 256 + tid;
        float v = (k < kmax) ? W[(size_t)k * G_ + g] : 0.0f;
        wt[(size_t)n * K_TOT + k] = f2bf(v);
    }
}

// ---------------- GEMM: out[m, 0:512] = ce @ W' + bias ----------------------
// BM=128, BN=128 (one output group per nb), BK=64, 4 waves (2x2 of 64x64).
// A: reg-staged fp32 -> cvt_pk bf16 -> swizzled ds_write_b128.
// B: global_load_lds with source-preswizzled offsets (linear LDS dest).
// Swizzle: 16B-slot ^= f(row); A/B rows are 128B: slot ^= (row&7).
__global__ __launch_bounds__(256, 2) void gemm_kernel(
    const float* __restrict__ events, const float* __restrict__ contexts,
    const u16* __restrict__ wt, const float* __restrict__ bias,
    float* __restrict__ out)
{
    __shared__ u16 Ab[2][128 * 64];   // bf16 A tile, swizzled
    __shared__ u16 Bb[2][128 * 64];   // bf16 B tile, swizzled

    const int tid  = threadIdx.x;
    const int bid  = blockIdx.x;
    // XCD-aware swizzle: 4 consecutive same-XCD blocks share one A panel.
    const int xcd  = bid & 7;
    const int nb   = (bid >> 3) & 3;
    const int mp   = xcd * 16 + (bid >> 5);
    const int m0   = mp * 128;

    const int lane = tid & 63;
    const int w    = tid >> 6;
    const int wm   = (w >> 1) * 64;
    const int wn   = (w & 1) * 64;
    const int lr   = lane & 15;
    const int kb   = (lane >> 4) * 8;      // u16 units within 32-wide K-chunk

    // ---- A staging setup: thread -> row r=tid>>1, half h=tid&1 (32 bf16) ----
    const int r = tid >> 1;
    const int h = tid & 1;
    int m = m0 + r; if (m > M_TOT - 1) m = M_TOT - 1;
    int bb = m / 1023;
    int tt = m - bb * 1023;
    const float* pa0 = events   + ((size_t)(bb * L_ + tt)) * H_;
    const float* pa1 = pa0 + H_;
    const float* pa2 = contexts + ((size_t)(bb * (L_ - 1) + tt)) * H_;
    // swizzled LDS u16 indices for the 4 ds_write_b128 of this thread
    int swrA[4];
    #pragma unroll
    for (int i = 0; i < 4; ++i)
        swrA[i] = r * 64 + ((((h << 2) + i) ^ (r & 7)) << 3);

    // ---- B staging setup: 4 gload_lds chunks/thread, source-preswizzled ----
    const u16* bB[4];
    #pragma unroll
    for (int it = 0; it < 4; ++it) {
        int c = it * 256 + tid;          // 0..1023
        int nloc = c >> 3;
        int co = (((c & 7) ^ (nloc & 7)) << 3);
        bB[it] = wt + (size_t)(nb * 128 + nloc) * K_TOT + co;
    }

    // ---- fragment read offsets (u16), swizzled ----
    int aoff[4][2], boff[4][2];
    #pragma unroll
    for (int i = 0; i < 4; ++i) {
        int row = wm + i * 16 + lr;
        int nn  = wn + i * 16 + lr;
        #pragma unroll
        for (int ks = 0; ks < 2; ++ks) {
            aoff[i][ks] = row * 64 + ((ks * 32 + kb) ^ ((row & 7) << 3));
            boff[i][ks] = nn  * 64 + ((ks * 32 + kb) ^ ((nn  & 7) << 3));
        }
    }

    f32x4 acc[4][4];
    #pragma unroll
    for (int i = 0; i < 4; ++i)
        #pragma unroll
        for (int j = 0; j < 4; ++j)
            acc[i][j] = (f32x4){0.f, 0.f, 0.f, 0.f};

    f32x4 areg[8];

    auto loadA = [&](int kt) {
        int k0 = kt * 64;
        int rg = k0 >> 10;
        int kq = (k0 & 1023) + h * 32;
        const float* s = (rg == 0) ? pa0 : (rg == 1 ? pa1 : pa2);
        s += kq;
        #pragma unroll
        for (int i = 0; i < 8; ++i) areg[i] = *(const f32x4*)(s + i * 4);
    };
    auto writeA = [&](int buf) {
        #pragma unroll
        for (int i = 0; i < 4; ++i) {
            union { short8 s; uint32_t u[4]; } wv;
            asm("v_cvt_pk_bf16_f32 %0, %1, %2" : "=v"(wv.u[0]) : "v"(areg[2*i][0]), "v"(areg[2*i][1]));
            asm("v_cvt_pk_bf16_f32 %0, %1, %2" : "=v"(wv.u[1]) : "v"(areg[2*i][2]), "v"(areg[2*i][3]));
            asm("v_cvt_pk_bf16_f32 %0, %1, %2" : "=v"(wv.u[2]) : "v"(areg[2*i+1][0]), "v"(areg[2*i+1][1]));
            asm("v_cvt_pk_bf16_f32 %0, %1, %2" : "=v"(wv.u[3]) : "v"(areg[2*i+1][2]), "v"(areg[2*i+1][3]));
            *(short8*)&Ab[buf][swrA[i]] = wv.s;
        }
    };
    auto stageB = [&](int buf, int kt) {
        int k0 = kt * 64;
        #pragma unroll
        for (int it = 0; it < 4; ++it)
            gload16(bB[it] + k0, &Bb[buf][(it * 256 + tid) * 8]);
    };
    auto compute = [&](int buf) {
        #pragma unroll
        for (int ks = 0; ks < 2; ++ks) {
            short8 a[4], bf[4];
            #pragma unroll
            for (int i = 0; i < 4; ++i)
                a[i] = *(const short8*)&Ab[buf][aoff[i][ks]];
            #pragma unroll
            for (int j = 0; j < 4; ++j)
                bf[j] = *(const short8*)&Bb[buf][boff[j][ks]];
            #pragma unroll
            for (int i = 0; i < 4; ++i)
                #pragma unroll
                for (int j = 0; j < 4; ++j)
                    acc[i][j] = __builtin_amdgcn_mfma_f32_16x16x32_bf16(
                        a[i], bf[j], acc[i][j], 0, 0, 0);
        }
    };

    // prologue
    stageB(0, 0);
    loadA(0);
    writeA(0);
    __syncthreads();

    int cur = 0;
    for (int kt = 0; kt < NKT; ++kt) {
        if (kt + 1 < NKT) {
            stageB(cur ^ 1, kt + 1);   // async B loads for next tile
            loadA(kt + 1);             // A global->reg for next tile
        }
        compute(cur);                  // ds_read + MFMA on current tile
        if (kt + 1 < NKT) writeA(cur ^ 1);  // cvt + swizzled ds_write
        __syncthreads();
        cur ^= 1;
    }

    // epilogue: C row = wm + i*16 + (lane>>4)*4 + r ; col = wn + j*16 + (lane&15)
    const float* bptr = bias + nb * 128;
    float* obase = out + (size_t)nb * OUT_SEG;
    #pragma unroll
    for (int i = 0; i < 4; ++i) {
        int mloc = wm + i * 16 + (lane >> 4) * 4;
        #pragma unroll
        for (int j = 0; j < 4; ++j) {
            int g = wn + j * 16 + lr;
            float bv = bptr[g];
            #pragma unroll
            for (int rr = 0; rr < 4; ++rr) {
                int mo = m0 + mloc + rr;
                if (mo < M_TOT) obase[(size_t)mo * G_ + g] = acc[i][j][rr] + bv;
            }
        }
    }
}

// ---------------- KL reduction: stage 1 (per-block partials, no atomics) -----
__global__ __launch_bounds__(256) void kl_kernel(const float* __restrict__ out,
                                                 float* __restrict__ partial)
{
    int wid  = threadIdx.x >> 6;
    int row  = blockIdx.x * 4 + wid;        // M_TOT = 4092*4 exactly
    int lane = threadIdx.x & 63;
    const float* zm  = out;
    const float* zlv = out + OUT_SEG;
    const float* qm  = out + (size_t)2 * OUT_SEG;
    const float* qlv = out + (size_t)3 * OUT_SEG;
    size_t base = (size_t)row * G_;
    float s = 0.f;
    #pragma unroll
    for (int hh = 0; hh < 2; ++hh) {
        int g = lane + hh * 64;
        float a = zm[base + g], b = zlv[base + g];
        float c = qm[base + g], d = qlv[base + g];
        float diff = a - c;
        s += d - b + (__expf(b) + diff * diff) * __expf(-d) - 1.0f;
    }
    #pragma unroll
    for (int off = 32; off > 0; off >>= 1)
        s += __shfl_down(s, off);
    __shared__ float pw[4];
    if (lane == 0) pw[wid] = s;
    __syncthreads();
    if (threadIdx.x == 0)
        partial[blockIdx.x] = pw[0] + pw[1] + pw[2] + pw[3];
}

// ---------------- KL reduction: stage 2 --------------------------------------
__global__ __launch_bounds__(256) void kl_final(const float* __restrict__ partial,
                                                float* __restrict__ out)
{
    float s = 0.f;
    for (int i = threadIdx.x; i < KL_BLOCKS; i += 256) s += partial[i];
    #pragma unroll
    for (int off = 32; off > 0; off >>= 1)
        s += __shfl_down(s, off);
    __shared__ float pw[4];
    int wid = threadIdx.x >> 6;
    int lane = threadIdx.x & 63;
    if (lane == 0) pw[wid] = s;
    __syncthreads();
    if (threadIdx.x == 0)
        out[KL_IDX] = 0.5f * (pw[0] + pw[1] + pw[2] + pw[3]) / (float)M_TOT;
}

// ---------------- launcher ----------------------------------------------------
extern "C" void kernel_launch(void* const* d_in, const int* in_sizes, int n_in,
                              void* d_out, int out_size, void* d_ws, size_t ws_size,
                              hipStream_t stream)
{
    const float* events   = (const float*)d_in[0];
    const float* contexts = (const float*)d_in[1];
    const float* Wzm = (const float*)d_in[2];
    const float* bzm = (const float*)d_in[3];
    const float* Wzv = (const float*)d_in[4];
    const float* bzv = (const float*)d_in[5];
    const float* Wqm = (const float*)d_in[6];
    const float* bqm = (const float*)d_in[7];
    const float* Wqv = (const float*)d_in[8];
    const float* bqv = (const float*)d_in[9];
    float* out = (float*)d_out;

    u16*   wt      = (u16*)((char*)d_ws + WS_WT_OFF);
    float* bias    = (float*)((char*)d_ws + WS_BIAS_OFF);
    float* partial = (float*)((char*)d_ws + WS_PART_OFF);

    prep_kernel<<<512, 256, 0, stream>>>(Wzm, bzm, Wzv, bzv, Wqm, bqm, Wqv, bqv,
                                         wt, bias);
    gemm_kernel<<<512, 256, 0, stream>>>(events, contexts, wt, bias, out);
    kl_kernel<<<KL_BLOCKS, 256, 0, stream>>>(out, partial);
    kl_final<<<1, 256, 0, stream>>>(partial, out);
}